// Round 7
// baseline (1484.865 us; speedup 1.0000x reference)
//
#include <hip/hip_runtime.h>
#include <hip/hip_bf16.h>

// Elman RNN, persistent kernel v4.1 — independent 16-row batch groups, 2 blocks/CU.
// h_t = tanh([h_{t-1} | x_t] @ [Wh|Wi]^T + (Wh_b+Wi_b)); out = h_T @ Wo^T + Wo_b
// T=128, B=512, E=256, H=1024, O=256.
//
// v4.1 fix (Rule #18): round-6's poll_flags used inline-asm loads + s_waitcnt
// followed by a REGISTER-ONLY min chain — hipcc may hoist register-only ops past
// an asm waitcnt ("memory" clobber doesn't order them; load dest VGPRs are not
// scoreboarded). Premature poll exit -> stale h tile -> absmax ~1.15. Fixed by
// using compiler-generated system-scope relaxed atomic loads/stores for the
// flag protocol (compiler owns the waitcnt placement). stage_h already carries
// the sched_barrier(0) fence.
//
// Structure (from v4): batch rows independent -> 32 groups x 16 rows; 512 blocks
// (2/CU), a CU's two blocks belong to different groups -> one computes while the
// other polls/stages. Wh frags register-resident; h handoff via sc0 sc1
// coherence-point loads/stores + per-(group,bn) flag words.

#define T_ 128
#define B_ 512
#define E_ 256
#define H_ 1024
#define O_ 256
#define RG 16            // rows per group
#define HB (B_ * H_)     // elems per h slot (1 MB bf16)

typedef __bf16 bf16x8 __attribute__((ext_vector_type(8)));
typedef float  f32x2  __attribute__((ext_vector_type(2)));
typedef float  f32x4  __attribute__((ext_vector_type(4)));
typedef unsigned int u32x4 __attribute__((ext_vector_type(4)));

static __device__ __forceinline__ unsigned short f2bf(float f) {
  unsigned u = __float_as_uint(f);
  u += 0x7fff + ((u >> 16) & 1);  // RNE
  return (unsigned short)(u >> 16);
}
static __device__ __forceinline__ unsigned pk2(float a, float b) {
  return (unsigned)f2bf(a) | ((unsigned)f2bf(b) << 16);
}
static __device__ __forceinline__ bf16x8 cvt8(const float* p) {
  float4 f0 = reinterpret_cast<const float4*>(p)[0];
  float4 f1 = reinterpret_cast<const float4*>(p)[1];
  union { u32x4 u; bf16x8 v; } r;
  r.u = (u32x4){pk2(f0.x, f0.y), pk2(f0.z, f0.w), pk2(f1.x, f1.y), pk2(f1.z, f1.w)};
  return r.v;
}
// tanh(x) = 1 - 2/(exp2(2*log2e*x)+1)
static __device__ __forceinline__ float fast_tanh(float x) {
  float e = __builtin_amdgcn_exp2f(x * 2.8853900817779268f);
  return 1.f - 2.f / (e + 1.f);
}

// Stage 16 rows x 1024 cols bf16 (32KB) into swizzled LDS via coherence-point loads.
static __device__ __forceinline__ void stage_h(const unsigned char* hb, int tid,
                                               unsigned char* As) {
  u32x4 s0, s1, s2, s3;
#define RNN_LD(J, SV)                                                           \
  {                                                                             \
    const unsigned char* p = hb + ((J) * 512 + tid) * 16;                       \
    asm volatile("global_load_dwordx4 %0, %1, off sc0 sc1"                      \
                 : "=v"(SV) : "v"(p) : "memory");                               \
  }
  RNN_LD(0, s0) RNN_LD(1, s1) RNN_LD(2, s2) RNN_LD(3, s3)
#undef RNN_LD
  asm volatile("s_waitcnt vmcnt(0)" ::: "memory");
  __builtin_amdgcn_sched_barrier(0);  // Rule #18: pin the waitcnt before LDS stores
#define RNN_ST(J, SV)                                                           \
  {                                                                             \
    int id = (J) * 512 + tid;                                                   \
    int row = id >> 7, c = id & 127;                                            \
    *reinterpret_cast<u32x4*>(&As[row * 2048 + ((c ^ (row & 7)) << 4)]) = SV;   \
  }
  RNN_ST(0, s0) RNN_ST(1, s1) RNN_ST(2, s2) RNN_ST(3, s3)
#undef RNN_ST
}

// Poll the 16 flag words of this group until min >= tgt.
// Compiler-generated system-scope atomic loads: waitcnt/dependency placement is
// the compiler's job -> no rule-#18 hazard (round-6 bug).
static __device__ __forceinline__ void poll_flags(const unsigned* fl, unsigned tgt) {
  for (;;) {
    unsigned m = 0xFFFFFFFFu;
#pragma unroll
    for (int i = 0; i < 16; ++i) {
      unsigned v = __hip_atomic_load(fl + i, __ATOMIC_RELAXED,
                                     __HIP_MEMORY_SCOPE_SYSTEM);
      m = min(m, v);
    }
    if (m >= tgt) return;
    __builtin_amdgcn_s_sleep(1);
  }
}

// ---------------------------------------------------------------------------
__global__ void prep_kernel(const float* __restrict__ seq,
                            unsigned short* __restrict__ seq_bf,
                            unsigned* __restrict__ flags) {
  size_t idx = (size_t)blockIdx.x * blockDim.x + threadIdx.x;
  size_t stride = (size_t)gridDim.x * blockDim.x;
  const size_t nchunk = (size_t)T_ * B_ * E_ / 8;
  for (size_t i = idx; i < nchunk; i += stride) {
    union { bf16x8 v; u32x4 u; } r;
    r.v = cvt8(seq + i * 8);
    *reinterpret_cast<u32x4*>(seq_bf + i * 8) = r.u;
  }
  if (idx < 512)
    __hip_atomic_store(&flags[idx], 0u, __ATOMIC_RELAXED, __HIP_MEMORY_SCOPE_SYSTEM);
}

// ---------------------------------------------------------------------------
__global__ __launch_bounds__(512, 4) void rnn_fused(
    const unsigned short* __restrict__ seq_bf, const float* __restrict__ Wh_w,
    const float* __restrict__ Wh_b, const float* __restrict__ Wi_w,
    const float* __restrict__ Wi_b, const float* __restrict__ Wo_w,
    const float* __restrict__ Wo_b,
    unsigned short* __restrict__ hbuf, unsigned* __restrict__ flags,
    float* __restrict__ out) {
  __shared__ __align__(16) unsigned char As[RG * 2048];  // 32 KB h tile (swizzled)
  __shared__ __align__(16) float red[2][RG][64];         // 8 KB k-split partials

  const int tid = threadIdx.x;
  const int bid = blockIdx.x;
  // bid and bid^256 map to different groups -> a CU's two resident blocks come
  // from independent groups regardless of packing order.
  const int half = bid >> 8, idx = bid & 255;
  const int bm = ((idx & 15) << 1) | half;  // group 0..31
  const int bn = idx >> 4;                  // 0..15
  const int R0 = bm * RG, C0 = bn * 64;
  const int lane = tid & 63, wave = tid >> 6;
  const int wn = (wave & 3) * 16;  // n-offset in [0,64)
  const int wk = wave >> 2;        // k-split 0/1 (K-slice 512)
  const int l15 = lane & 15, k4 = lane >> 4;  // 16x16 frag: row/col=l15, k+=k4*8
  const int mycol = C0 + wn + l15;

  // ---- prologue: Wh / Wi fragments -> registers for all 128 steps
  bf16x8 bh[16];
  {
    const float* whp = Wh_w + (size_t)mycol * H_ + wk * 512 + k4 * 8;
#pragma unroll
    for (int ks = 0; ks < 16; ++ks) bh[ks] = cvt8(whp + ks * 32);
  }
  bf16x8 wif[4];
  {
    const float* wip = Wi_w + (size_t)mycol * E_ + wk * 128 + k4 * 8;
#pragma unroll
    for (int ks = 0; ks < 4; ++ks) wif[ks] = cvt8(wip + ks * 32);
  }
  // epilogue assignment: thread -> (erow, cols ec0, ec0+1)
  const int erow = tid >> 5, ec0 = (tid & 31) * 2;
  const float bias0 = Wh_b[C0 + ec0] + Wi_b[C0 + ec0];
  const float bias1 = Wh_b[C0 + ec0 + 1] + Wi_b[C0 + ec0 + 1];
  const unsigned* grpfl = flags + bm * 16;
  unsigned* myfl = flags + bm * 16 + bn;
  const size_t hoff_b = ((size_t)(R0 + erow) * H_ + C0 + ec0) * 2;  // bytes

  for (int t = 0; t < T_; ++t) {
    f32x4 acc = {0.f, 0.f, 0.f, 0.f};
    // ---- x-part (independent of h; overlaps partner block + producers)
    {
      const unsigned short* xp =
          seq_bf + ((size_t)t * B_ + R0 + l15) * E_ + wk * 128 + k4 * 8;
#pragma unroll
      for (int ks = 0; ks < 4; ++ks) {
        bf16x8 a = *reinterpret_cast<const bf16x8*>(xp + ks * 32);
        acc = __builtin_amdgcn_mfma_f32_16x16x32_bf16(a, wif[ks], acc, 0, 0, 0);
      }
    }
    if (t > 0) {
      poll_flags(grpfl, (unsigned)t);
      const unsigned char* hb =
          (const unsigned char*)(hbuf + (size_t)((t - 1) & 1) * HB) + (size_t)R0 * 2048;
      stage_h(hb, tid, As);
    }
    __syncthreads();
    if (t > 0) {
      // ---- h-part: 16 MFMA over this wave's K-slice (Wh frags in regs)
#pragma unroll
      for (int ks = 0; ks < 16; ++ks) {
        int c = wk * 64 + ks * 4 + k4;
        bf16x8 a = *reinterpret_cast<const bf16x8*>(
            &As[l15 * 2048 + ((c ^ (l15 & 7)) << 4)]);
        acc = __builtin_amdgcn_mfma_f32_16x16x32_bf16(a, bh[ks], acc, 0, 0, 0);
      }
    }
    // ---- k-split partials (C layout: col=l15, row=k4*4+r)
#pragma unroll
    for (int r = 0; r < 4; ++r) red[wk][k4 * 4 + r][wn + l15] = acc[r];
    __syncthreads();
    // ---- distributed epilogue: each thread 2 outputs -> 4B store
    {
      f32x2 v0 = *reinterpret_cast<const f32x2*>(&red[0][erow][ec0]);
      f32x2 v1 = *reinterpret_cast<const f32x2*>(&red[1][erow][ec0]);
      float h0 = fast_tanh(v0[0] + v1[0] + bias0);
      float h1 = fast_tanh(v0[1] + v1[1] + bias1);
      unsigned pv = pk2(h0, h1);
      const unsigned char* dst =
          (const unsigned char*)hbuf + (size_t)(t & 1) * (HB * 2) + hoff_b;
      asm volatile("global_store_dword %0, %1, off sc0 sc1"
                   :: "v"(dst), "v"(pv) : "memory");
    }
    asm volatile("s_waitcnt vmcnt(0)" ::: "memory");  // h stores acked at coherence pt
    __syncthreads();
    if (tid == 0)
      __hip_atomic_store(myfl, (unsigned)(t + 1), __ATOMIC_RELAXED,
                         __HIP_MEMORY_SCOPE_SYSTEM);
  }

  // ---- final GEMM: out = h_T @ Wo^T + Wo_b (blocks bn<4, fp32 out)
  if (bn >= 4) return;
  {
    poll_flags(grpfl, (unsigned)T_);
    const unsigned char* hb =
        (const unsigned char*)(hbuf + (size_t)((T_ - 1) & 1) * HB) + (size_t)R0 * 2048;
    stage_h(hb, tid, As);
    __syncthreads();
    f32x4 acc = {0.f, 0.f, 0.f, 0.f};
    const int oc = C0 + wn + l15;  // [0,256)
    const float* wop = Wo_w + (size_t)oc * H_ + wk * 512 + k4 * 8;
#pragma unroll
    for (int ks = 0; ks < 16; ++ks) {
      int c = wk * 64 + ks * 4 + k4;
      bf16x8 a = *reinterpret_cast<const bf16x8*>(
          &As[l15 * 2048 + ((c ^ (l15 & 7)) << 4)]);
      bf16x8 b = cvt8(wop + ks * 32);
      acc = __builtin_amdgcn_mfma_f32_16x16x32_bf16(a, b, acc, 0, 0, 0);
    }
#pragma unroll
    for (int r = 0; r < 4; ++r) red[wk][k4 * 4 + r][wn + l15] = acc[r];
    __syncthreads();
    {
      f32x2 v0 = *reinterpret_cast<const f32x2*>(&red[0][erow][ec0]);
      f32x2 v1 = *reinterpret_cast<const f32x2*>(&red[1][erow][ec0]);
      f32x2 o;
      o[0] = v0[0] + v1[0] + Wo_b[C0 + ec0];
      o[1] = v0[1] + v1[1] + Wo_b[C0 + ec0 + 1];
      *reinterpret_cast<f32x2*>(out + (size_t)(R0 + erow) * O_ + C0 + ec0) = o;
    }
  }
}

// ---------------------------------------------------------------------------
extern "C" void kernel_launch(void* const* d_in, const int* in_sizes, int n_in,
                              void* d_out, int out_size, void* d_ws, size_t ws_size,
                              hipStream_t stream) {
  const float* seq  = (const float*)d_in[0];
  const float* Wh_w = (const float*)d_in[1];
  const float* Wh_b = (const float*)d_in[2];
  const float* Wi_w = (const float*)d_in[3];
  const float* Wi_b = (const float*)d_in[4];
  const float* Wo_w = (const float*)d_in[5];
  const float* Wo_b = (const float*)d_in[6];

  char* ws = (char*)d_ws;
  unsigned short* hbuf   = (unsigned short*)ws; ws += (size_t)2 * HB * 2;  // 2 MB
  unsigned*       flags  = (unsigned*)ws;       ws += 4096;                // 512 words
  unsigned short* seq_bf = (unsigned short*)ws;                            // 32 MB

  prep_kernel<<<2048, 256, 0, stream>>>(seq, seq_bf, flags);
  rnn_fused<<<512, 512, 0, stream>>>(seq_bf, Wh_w, Wh_b, Wi_w, Wi_b, Wo_w, Wo_b,
                                     hbuf, flags, (float*)d_out);
}

// Round 8
// 1339.171 us; speedup vs baseline: 1.1088x; 1.1088x over previous
//
#include <hip/hip_runtime.h>
#include <hip/hip_bf16.h>

// Elman RNN, persistent kernel v5 — 32 independent 16-row groups, 2 blocks/CU,
// single per-group counter (agent scope, MALL-served), stage/x-part overlap.
// h_t = tanh([h_{t-1} | x_t] @ [Wh|Wi]^T + (Wh_b+Wi_b)); out = h_T @ Wo^T + Wo_b
// T=128, B=512, E=256, H=1024, O=256.
//
// Lessons encoded here:
//  r2: RELEASE/agent atomics emit buffer_wbl2 -> 16us/step. Use RELAXED.
//  r4/5: sc0 sc1 loads/stores = coherence-point handoff works (absmax stable).
//  r6: inline-asm load + waitcnt + REGISTER-ONLY consumer = rule #18 race.
//      Any asm-load whose consumer is not a memory op needs sched_barrier(0)
//      after the waitcnt; or use compiler atomics.
//  r7: SYSTEM-scope atomic loads are HBM-served and scalarized (~6us/poll).
//      AGENT scope is the right coherence point (MALL) for cross-XCD flags.

#define T_ 128
#define B_ 512
#define E_ 256
#define H_ 1024
#define O_ 256
#define RG 16            // rows per group
#define HB (B_ * H_)     // elems per h slot (1 MB bf16)

typedef __bf16 bf16x8 __attribute__((ext_vector_type(8)));
typedef float  f32x2  __attribute__((ext_vector_type(2)));
typedef float  f32x4  __attribute__((ext_vector_type(4)));
typedef unsigned int u32x4 __attribute__((ext_vector_type(4)));

static __device__ __forceinline__ unsigned short f2bf(float f) {
  unsigned u = __float_as_uint(f);
  u += 0x7fff + ((u >> 16) & 1);  // RNE
  return (unsigned short)(u >> 16);
}
static __device__ __forceinline__ unsigned pk2(float a, float b) {
  return (unsigned)f2bf(a) | ((unsigned)f2bf(b) << 16);
}
static __device__ __forceinline__ bf16x8 cvt8(const float* p) {
  float4 f0 = reinterpret_cast<const float4*>(p)[0];
  float4 f1 = reinterpret_cast<const float4*>(p)[1];
  union { u32x4 u; bf16x8 v; } r;
  r.u = (u32x4){pk2(f0.x, f0.y), pk2(f0.z, f0.w), pk2(f1.x, f1.y), pk2(f1.z, f1.w)};
  return r.v;
}
// tanh(x) = 1 - 2/(exp2(2*log2e*x)+1)
static __device__ __forceinline__ float fast_tanh(float x) {
  float e = __builtin_amdgcn_exp2f(x * 2.8853900817779268f);
  return 1.f - 2.f / (e + 1.f);
}

// ---- h staging, split so x-part MFMAs can hide the MALL read latency ----
static __device__ __forceinline__ void stage_issue(const unsigned char* hb, int tid,
                                                   u32x4& s0, u32x4& s1,
                                                   u32x4& s2, u32x4& s3) {
  asm volatile("global_load_dwordx4 %0, %1, off sc0 sc1"
               : "=v"(s0) : "v"(hb + (size_t)(0 * 512 + tid) * 16) : "memory");
  asm volatile("global_load_dwordx4 %0, %1, off sc0 sc1"
               : "=v"(s1) : "v"(hb + (size_t)(1 * 512 + tid) * 16) : "memory");
  asm volatile("global_load_dwordx4 %0, %1, off sc0 sc1"
               : "=v"(s2) : "v"(hb + (size_t)(2 * 512 + tid) * 16) : "memory");
  asm volatile("global_load_dwordx4 %0, %1, off sc0 sc1"
               : "=v"(s3) : "v"(hb + (size_t)(3 * 512 + tid) * 16) : "memory");
}
static __device__ __forceinline__ void stage_finish(int tid, unsigned char* As,
                                                    u32x4 s0, u32x4 s1,
                                                    u32x4 s2, u32x4 s3) {
  asm volatile("s_waitcnt vmcnt(0)" ::: "memory");
  __builtin_amdgcn_sched_barrier(0);  // rule #18: nothing hoists above the waitcnt
#define RNN_ST(J, SV)                                                           \
  {                                                                             \
    int id = (J) * 512 + tid;                                                   \
    int row = id >> 7, c = id & 127;                                            \
    *reinterpret_cast<u32x4*>(&As[row * 2048 + ((c ^ (row & 7)) << 4)]) = SV;   \
  }
  RNN_ST(0, s0) RNN_ST(1, s1) RNN_ST(2, s2) RNN_ST(3, s3)
#undef RNN_ST
}

// Poll the group's step counter (one word, MALL-served, compiler-managed deps).
static __device__ __forceinline__ void poll_cnt(const unsigned* c, unsigned tgt) {
  while (__hip_atomic_load(c, __ATOMIC_RELAXED, __HIP_MEMORY_SCOPE_AGENT) < tgt)
    __builtin_amdgcn_s_sleep(1);
}

// ---------------------------------------------------------------------------
__global__ void prep_kernel(const float* __restrict__ seq,
                            unsigned short* __restrict__ seq_bf,
                            unsigned* __restrict__ cnt) {
  size_t idx = (size_t)blockIdx.x * blockDim.x + threadIdx.x;
  size_t stride = (size_t)gridDim.x * blockDim.x;
  const size_t nchunk = (size_t)T_ * B_ * E_ / 8;
  for (size_t i = idx; i < nchunk; i += stride) {
    union { bf16x8 v; u32x4 u; } r;
    r.v = cvt8(seq + i * 8);
    *reinterpret_cast<u32x4*>(seq_bf + i * 8) = r.u;
  }
  if (idx < 32)
    __hip_atomic_store(&cnt[idx * 32], 0u, __ATOMIC_RELAXED, __HIP_MEMORY_SCOPE_AGENT);
}

// ---------------------------------------------------------------------------
__global__ __launch_bounds__(512, 4) void rnn_fused(
    const unsigned short* __restrict__ seq_bf, const float* __restrict__ Wh_w,
    const float* __restrict__ Wh_b, const float* __restrict__ Wi_w,
    const float* __restrict__ Wi_b, const float* __restrict__ Wo_w,
    const float* __restrict__ Wo_b,
    unsigned short* __restrict__ hbuf, unsigned* __restrict__ cnt,
    float* __restrict__ out) {
  __shared__ __align__(16) unsigned char As[RG * 2048];  // 32 KB h tile (swizzled)
  __shared__ __align__(16) float red[2][RG][64];         // 8 KB k-split partials

  const int tid = threadIdx.x;
  const int bid = blockIdx.x;
  // bid and bid^256 map to different groups -> a CU's two resident blocks come
  // from independent groups regardless of packing order.
  const int half = bid >> 8, idx = bid & 255;
  const int bm = ((idx & 15) << 1) | half;  // group 0..31
  const int bn = idx >> 4;                  // 0..15
  const int R0 = bm * RG, C0 = bn * 64;
  const int lane = tid & 63, wave = tid >> 6;
  const int wn = (wave & 3) * 16;  // n-offset in [0,64)
  const int wk = wave >> 2;        // k-split 0/1 (K-slice 512)
  const int l15 = lane & 15, k4 = lane >> 4;  // 16x16 frag: row/col=l15, k+=k4*8
  const int mycol = C0 + wn + l15;

  // ---- prologue: Wh / Wi fragments -> registers/AGPRs for all 128 steps
  bf16x8 bh[16];
  {
    const float* whp = Wh_w + (size_t)mycol * H_ + wk * 512 + k4 * 8;
#pragma unroll
    for (int ks = 0; ks < 16; ++ks) bh[ks] = cvt8(whp + ks * 32);
  }
  bf16x8 wif[4];
  {
    const float* wip = Wi_w + (size_t)mycol * E_ + wk * 128 + k4 * 8;
#pragma unroll
    for (int ks = 0; ks < 4; ++ks) wif[ks] = cvt8(wip + ks * 32);
  }
  // epilogue assignment: thread -> (erow, cols ec0, ec0+1)
  const int erow = tid >> 5, ec0 = (tid & 31) * 2;
  const float bias0 = Wh_b[C0 + ec0] + Wi_b[C0 + ec0];
  const float bias1 = Wh_b[C0 + ec0 + 1] + Wi_b[C0 + ec0 + 1];
  unsigned* myc = &cnt[bm * 32];
  const size_t hoff_b = ((size_t)(R0 + erow) * H_ + C0 + ec0) * 2;  // bytes

  for (int t = 0; t < T_; ++t) {
    f32x4 acc = {0.f, 0.f, 0.f, 0.f};
    u32x4 s0, s1, s2, s3;
    if (t > 0) {
      // wait for all 16 producers of this group to finish step t-1, then
      // issue the h-tile loads (latency hidden under the x-part below)
      poll_cnt(myc, 16u * (unsigned)t);
      const unsigned char* hb =
          (const unsigned char*)(hbuf + (size_t)((t - 1) & 1) * HB) + (size_t)R0 * 2048;
      stage_issue(hb, tid, s0, s1, s2, s3);
    }
    // ---- x-part (independent of h) overlaps the staged loads in flight
    {
      const unsigned short* xp =
          seq_bf + ((size_t)t * B_ + R0 + l15) * E_ + wk * 128 + k4 * 8;
#pragma unroll
      for (int ks = 0; ks < 4; ++ks) {
        bf16x8 a = *reinterpret_cast<const bf16x8*>(xp + ks * 32);
        acc = __builtin_amdgcn_mfma_f32_16x16x32_bf16(a, wif[ks], acc, 0, 0, 0);
      }
    }
    if (t > 0) stage_finish(tid, As, s0, s1, s2, s3);
    __syncthreads();
    if (t > 0) {
      // ---- h-part: 16 MFMA over this wave's K-slice (Wh frags in regs)
#pragma unroll
      for (int ks = 0; ks < 16; ++ks) {
        int c = wk * 64 + ks * 4 + k4;
        bf16x8 a = *reinterpret_cast<const bf16x8*>(
            &As[l15 * 2048 + ((c ^ (l15 & 7)) << 4)]);
        acc = __builtin_amdgcn_mfma_f32_16x16x32_bf16(a, bh[ks], acc, 0, 0, 0);
      }
    }
    // ---- k-split partials (C layout: col=l15, row=k4*4+r)
#pragma unroll
    for (int r = 0; r < 4; ++r) red[wk][k4 * 4 + r][wn + l15] = acc[r];
    __syncthreads();
    // ---- distributed epilogue: each thread 2 outputs -> 4B store
    {
      f32x2 v0 = *reinterpret_cast<const f32x2*>(&red[0][erow][ec0]);
      f32x2 v1 = *reinterpret_cast<const f32x2*>(&red[1][erow][ec0]);
      float h0 = fast_tanh(v0[0] + v1[0] + bias0);
      float h1 = fast_tanh(v0[1] + v1[1] + bias1);
      unsigned pv = pk2(h0, h1);
      const unsigned char* dst =
          (const unsigned char*)hbuf + (size_t)(t & 1) * (HB * 2) + hoff_b;
      asm volatile("global_store_dword %0, %1, off sc0 sc1"
                   :: "v"(dst), "v"(pv) : "memory");
    }
    asm volatile("s_waitcnt vmcnt(0)" ::: "memory");  // h stores acked at coherence pt
    __syncthreads();
    if (tid == 0)
      __hip_atomic_fetch_add(myc, 1u, __ATOMIC_RELAXED, __HIP_MEMORY_SCOPE_AGENT);
  }

  // ---- final GEMM: out = h_T @ Wo^T + Wo_b (blocks bn<4, fp32 out)
  if (bn >= 4) return;
  {
    poll_cnt(myc, 16u * (unsigned)T_);
    const unsigned char* hb =
        (const unsigned char*)(hbuf + (size_t)((T_ - 1) & 1) * HB) + (size_t)R0 * 2048;
    u32x4 s0, s1, s2, s3;
    stage_issue(hb, tid, s0, s1, s2, s3);
    stage_finish(tid, As, s0, s1, s2, s3);
    __syncthreads();
    f32x4 acc = {0.f, 0.f, 0.f, 0.f};
    const int oc = C0 + wn + l15;  // [0,256)
    const float* wop = Wo_w + (size_t)oc * H_ + wk * 512 + k4 * 8;
#pragma unroll
    for (int ks = 0; ks < 16; ++ks) {
      int c = wk * 64 + ks * 4 + k4;
      bf16x8 a = *reinterpret_cast<const bf16x8*>(
          &As[l15 * 2048 + ((c ^ (l15 & 7)) << 4)]);
      bf16x8 b = cvt8(wop + ks * 32);
      acc = __builtin_amdgcn_mfma_f32_16x16x32_bf16(a, b, acc, 0, 0, 0);
    }
#pragma unroll
    for (int r = 0; r < 4; ++r) red[wk][k4 * 4 + r][wn + l15] = acc[r];
    __syncthreads();
    {
      f32x2 v0 = *reinterpret_cast<const f32x2*>(&red[0][erow][ec0]);
      f32x2 v1 = *reinterpret_cast<const f32x2*>(&red[1][erow][ec0]);
      f32x2 o;
      o[0] = v0[0] + v1[0] + Wo_b[C0 + ec0];
      o[1] = v0[1] + v1[1] + Wo_b[C0 + ec0 + 1];
      *reinterpret_cast<f32x2*>(out + (size_t)(R0 + erow) * O_ + C0 + ec0) = o;
    }
  }
}

// ---------------------------------------------------------------------------
extern "C" void kernel_launch(void* const* d_in, const int* in_sizes, int n_in,
                              void* d_out, int out_size, void* d_ws, size_t ws_size,
                              hipStream_t stream) {
  const float* seq  = (const float*)d_in[0];
  const float* Wh_w = (const float*)d_in[1];
  const float* Wh_b = (const float*)d_in[2];
  const float* Wi_w = (const float*)d_in[3];
  const float* Wi_b = (const float*)d_in[4];
  const float* Wo_w = (const float*)d_in[5];
  const float* Wo_b = (const float*)d_in[6];

  char* ws = (char*)d_ws;
  unsigned short* hbuf   = (unsigned short*)ws; ws += (size_t)2 * HB * 2;  // 2 MB
  unsigned*       cnt    = (unsigned*)ws;       ws += 4096;                // 32 x 128B
  unsigned short* seq_bf = (unsigned short*)ws;                            // 32 MB

  prep_kernel<<<2048, 256, 0, stream>>>(seq, seq_bf, cnt);
  rnn_fused<<<512, 512, 0, stream>>>(seq_bf, Wh_w, Wh_b, Wi_w, Wi_b, Wo_w, Wo_b,
                                     hbuf, cnt, (float*)d_out);
}

// Round 9
// 658.126 us; speedup vs baseline: 2.2562x; 2.0348x over previous
//
#include <hip/hip_runtime.h>
#include <hip/hip_bf16.h>

// Elman RNN, persistent kernel v6 — r5 protocol restored + rule-#18 fence,
// 32 groups x 16 rows x 8 blocks (128 cols each), full-K waves (no k-split).
// h_t = tanh([h_{t-1} | x_t] @ [Wh|Wi]^T + (Wh_b+Wi_b)); out = h_T @ Wo^T + Wo_b
// T=128, B=512, E=256, H=1024, O=256.
//
// Hard-won protocol lessons:
//  r2: RELEASE/agent atomics emit L2 writeback flushes -> 16us/step. Never.
//  r4/r5: asm sc0 sc1 loads/stores = coherence handoff; group's blocks
//         co-locate per XCD (bid stride % 8 == 0) -> flags/h served by LOCAL
//         L2 (~200cyc), FETCH stays ~100MB. FAST path.
//  r6: asm load + s_waitcnt + register-only consumer = rule #18 race (compiler
//      hoists non-memory ops past the waitcnt). MUST sched_barrier(0) after.
//  r7/r8: compiler SYSTEM/AGENT atomic polls are MALL/HBM round-trips
//      (~6us/step, FETCH 420-510MB). Never on the hot path.

#define T_ 128
#define B_ 512
#define E_ 256
#define H_ 1024
#define O_ 256
#define RG 16            // rows per group
#define HB (B_ * H_)     // elems per h slot (1 MB bf16)

typedef __bf16 bf16x8 __attribute__((ext_vector_type(8)));
typedef float  f32x4  __attribute__((ext_vector_type(4)));
typedef unsigned int u32x2 __attribute__((ext_vector_type(2)));
typedef unsigned int u32x4 __attribute__((ext_vector_type(4)));

static __device__ __forceinline__ unsigned short f2bf(float f) {
  unsigned u = __float_as_uint(f);
  u += 0x7fff + ((u >> 16) & 1);  // RNE
  return (unsigned short)(u >> 16);
}
static __device__ __forceinline__ unsigned pk2(float a, float b) {
  return (unsigned)f2bf(a) | ((unsigned)f2bf(b) << 16);
}
static __device__ __forceinline__ bf16x8 cvt8(const float* p) {
  float4 f0 = reinterpret_cast<const float4*>(p)[0];
  float4 f1 = reinterpret_cast<const float4*>(p)[1];
  union { u32x4 u; bf16x8 v; } r;
  r.u = (u32x4){pk2(f0.x, f0.y), pk2(f0.z, f0.w), pk2(f1.x, f1.y), pk2(f1.z, f1.w)};
  return r.v;
}
// tanh(x) = 1 - 2/(exp2(2*log2e*x)+1)
static __device__ __forceinline__ float fast_tanh(float x) {
  float e = __builtin_amdgcn_exp2f(x * 2.8853900817779268f);
  return 1.f - 2.f / (e + 1.f);
}

// ---- h staging (16 rows x 1024 cols bf16 = 32KB), split issue/finish ----
static __device__ __forceinline__ void stage_issue(const unsigned char* hb, int tid,
                                                   u32x4& s0, u32x4& s1,
                                                   u32x4& s2, u32x4& s3) {
  asm volatile("global_load_dwordx4 %0, %1, off sc0 sc1"
               : "=v"(s0) : "v"(hb + (size_t)(0 * 512 + tid) * 16) : "memory");
  asm volatile("global_load_dwordx4 %0, %1, off sc0 sc1"
               : "=v"(s1) : "v"(hb + (size_t)(1 * 512 + tid) * 16) : "memory");
  asm volatile("global_load_dwordx4 %0, %1, off sc0 sc1"
               : "=v"(s2) : "v"(hb + (size_t)(2 * 512 + tid) * 16) : "memory");
  asm volatile("global_load_dwordx4 %0, %1, off sc0 sc1"
               : "=v"(s3) : "v"(hb + (size_t)(3 * 512 + tid) * 16) : "memory");
}
static __device__ __forceinline__ void stage_finish(int tid, unsigned char* As,
                                                    u32x4 s0, u32x4 s1,
                                                    u32x4 s2, u32x4 s3) {
  asm volatile("s_waitcnt vmcnt(0)" ::: "memory");
  __builtin_amdgcn_sched_barrier(0);  // rule #18 fence
#define RNN_ST(J, SV)                                                           \
  {                                                                             \
    int id = (J) * 512 + tid;                                                   \
    int row = id >> 7, c = id & 127;                                            \
    *reinterpret_cast<u32x4*>(&As[row * 2048 + ((c ^ (row & 7)) << 4)]) = SV;   \
  }
  RNN_ST(0, s0) RNN_ST(1, s1) RNN_ST(2, s2) RNN_ST(3, s3)
#undef RNN_ST
}

// Poll the 8 flag words of this group (asm sc0 sc1 -> local-L2-served) with
// the rule-#18 fence before the register-only min chain.
static __device__ __forceinline__ void poll_flags(const unsigned* fl, unsigned tgt) {
  for (;;) {
    u32x4 a, b;
    asm volatile("global_load_dwordx4 %0, %1, off sc0 sc1" : "=v"(a) : "v"(fl) : "memory");
    asm volatile("global_load_dwordx4 %0, %1, off sc0 sc1" : "=v"(b) : "v"(fl + 4) : "memory");
    asm volatile("s_waitcnt vmcnt(0)" ::: "memory");
    __builtin_amdgcn_sched_barrier(0);  // rule #18 fence (r6 bug)
    unsigned m = a.x;
    m = min(m, a.y); m = min(m, a.z); m = min(m, a.w);
    m = min(m, b.x); m = min(m, b.y); m = min(m, b.z); m = min(m, b.w);
    if (m >= tgt) return;
    __builtin_amdgcn_s_sleep(1);
  }
}

// ---------------------------------------------------------------------------
__global__ void prep_kernel(const float* __restrict__ seq,
                            unsigned short* __restrict__ seq_bf,
                            unsigned* __restrict__ flags) {
  size_t idx = (size_t)blockIdx.x * blockDim.x + threadIdx.x;
  size_t stride = (size_t)gridDim.x * blockDim.x;
  const size_t nchunk = (size_t)T_ * B_ * E_ / 8;
  for (size_t i = idx; i < nchunk; i += stride) {
    union { bf16x8 v; u32x4 u; } r;
    r.v = cvt8(seq + i * 8);
    *reinterpret_cast<u32x4*>(seq_bf + i * 8) = r.u;
  }
  if (idx < 1024) {
    unsigned z = 0;
    asm volatile("global_store_dword %0, %1, off sc0 sc1"
                 :: "v"(flags + idx), "v"(z) : "memory");
  }
}

// ---------------------------------------------------------------------------
__global__ __launch_bounds__(512, 2) void rnn_fused(
    const unsigned short* __restrict__ seq_bf, const float* __restrict__ Wh_w,
    const float* __restrict__ Wh_b, const float* __restrict__ Wi_w,
    const float* __restrict__ Wi_b, const float* __restrict__ Wo_w,
    const float* __restrict__ Wo_b,
    unsigned short* __restrict__ hbuf, unsigned* __restrict__ flags,
    float* __restrict__ out) {
  __shared__ __align__(16) unsigned char As[RG * 2048];  // 32 KB h tile (swizzled)
  __shared__ __align__(16) float hred[RG][132];          // 8.25 KB (pad: no conflicts)

  const int tid = threadIdx.x;
  const int bid = blockIdx.x;
  // group g: 8 blocks with bid % 8 == g & 7 -> same XCD (heuristic; sc0 sc1
  // keeps correctness either way, locality is perf-only).
  const int g  = (bid & 7) + 8 * ((bid >> 3) & 3);  // 0..31
  const int co = bid >> 5;                          // 0..7 (128-col slice)
  const int R0 = g * RG, C0 = co * 128;
  const int lane = tid & 63, wv = tid >> 6;
  const int l15 = lane & 15, k4 = lane >> 4;  // 16x16 frag: row/col=l15, k+=k4*8
  const int mycol = C0 + wv * 16 + l15;       // this thread's output column

  // ---- prologue: full-K weight fragments -> registers for all 128 steps
  bf16x8 bh[32];  // Wh[mycol][0..1024) : 128 VGPR
  {
    const float* whp = Wh_w + (size_t)mycol * H_ + k4 * 8;
#pragma unroll
    for (int ks = 0; ks < 32; ++ks) bh[ks] = cvt8(whp + ks * 32);
  }
  bf16x8 wif[8];  // Wi[mycol][0..256) : 32 VGPR
  {
    const float* wip = Wi_w + (size_t)mycol * E_ + k4 * 8;
#pragma unroll
    for (int ks = 0; ks < 8; ++ks) wif[ks] = cvt8(wip + ks * 32);
  }
  const float bias_c = Wh_b[mycol] + Wi_b[mycol];  // (unused in epilogue path)
  (void)bias_c;
  // epilogue mapping: thread -> (erow, cols ec..ec+3)
  const int erow = tid >> 5, ec = (tid & 31) * 4;
  f32x4 bias4;
  {
    f32x4 b1 = *reinterpret_cast<const f32x4*>(Wh_b + C0 + ec);
    f32x4 b2 = *reinterpret_cast<const f32x4*>(Wi_b + C0 + ec);
    bias4 = b1 + b2;
  }
  const unsigned* grpfl = flags + g * 32;
  unsigned* myfl = flags + g * 32 + co;
  const size_t hoff_b = ((size_t)(R0 + erow) * H_ + C0 + ec) * 2;  // bytes

  for (int t = 0; t < T_; ++t) {
    f32x4 acc = {0.f, 0.f, 0.f, 0.f};
    u32x4 s0, s1, s2, s3;
    if (t > 0) {
      poll_flags(grpfl, (unsigned)t);
      const unsigned char* hb =
          (const unsigned char*)(hbuf + (size_t)((t - 1) & 1) * HB) + (size_t)R0 * 2048;
      stage_issue(hb, tid, s0, s1, s2, s3);
    }
    // ---- x-part: 8 MFMA over E=256 (overlaps the h loads in flight)
    {
      const unsigned short* xp =
          seq_bf + ((size_t)t * B_ + R0 + l15) * E_ + k4 * 8;
#pragma unroll
      for (int ks = 0; ks < 8; ++ks) {
        bf16x8 a = *reinterpret_cast<const bf16x8*>(xp + ks * 32);
        acc = __builtin_amdgcn_mfma_f32_16x16x32_bf16(a, wif[ks], acc, 0, 0, 0);
      }
    }
    if (t > 0) stage_finish(tid, As, s0, s1, s2, s3);
    __syncthreads();
    if (t > 0) {
      // ---- h-part: 32 MFMA, full K=1024, Wh frags from registers
#pragma unroll
      for (int ks = 0; ks < 32; ++ks) {
        int c = ks * 4 + k4;
        bf16x8 a = *reinterpret_cast<const bf16x8*>(
            &As[l15 * 2048 + ((c ^ (l15 & 7)) << 4)]);
        acc = __builtin_amdgcn_mfma_f32_16x16x32_bf16(a, bh[ks], acc, 0, 0, 0);
      }
    }
    // ---- acc -> LDS (C layout: col=l15, row=k4*4+r), padded rows: conflict-free
#pragma unroll
    for (int r = 0; r < 4; ++r) hred[k4 * 4 + r][wv * 16 + l15] = acc[r];
    __syncthreads();
    // ---- distributed epilogue: 4 cols per thread -> tanh -> one 8B store
    {
      f32x4 v = *reinterpret_cast<const f32x4*>(&hred[erow][ec]);
      v += bias4;
      u32x2 pv = {pk2(fast_tanh(v[0]), fast_tanh(v[1])),
                  pk2(fast_tanh(v[2]), fast_tanh(v[3]))};
      const unsigned char* dst =
          (const unsigned char*)hbuf + (size_t)(t & 1) * (HB * 2) + hoff_b;
      asm volatile("global_store_dwordx2 %0, %1, off sc0 sc1"
                   :: "v"(dst), "v"(pv) : "memory");
    }
    asm volatile("s_waitcnt vmcnt(0)" ::: "memory");  // h stores acked
    __syncthreads();
    if (tid == 0) {
      unsigned fv = (unsigned)(t + 1);
      asm volatile("global_store_dword %0, %1, off sc0 sc1"
                   :: "v"(myfl), "v"(fv) : "memory");
    }
  }

  // ---- final GEMM: out = h_T @ Wo^T + Wo_b (co<2 blocks cover 512x256, fp32)
  if (co >= 2) return;
  {
    poll_flags(grpfl, (unsigned)T_);
    const unsigned char* hb =
        (const unsigned char*)(hbuf + (size_t)((T_ - 1) & 1) * HB) + (size_t)R0 * 2048;
    u32x4 s0, s1, s2, s3;
    stage_issue(hb, tid, s0, s1, s2, s3);
    stage_finish(tid, As, s0, s1, s2, s3);
    __syncthreads();
    f32x4 acc = {0.f, 0.f, 0.f, 0.f};
    const int oc = C0 + wv * 16 + l15;  // [0,256)
    const float* wop = Wo_w + (size_t)oc * H_ + k4 * 8;
#pragma unroll 8
    for (int ks = 0; ks < 32; ++ks) {
      int c = ks * 4 + k4;
      bf16x8 a = *reinterpret_cast<const bf16x8*>(
          &As[l15 * 2048 + ((c ^ (l15 & 7)) << 4)]);
      bf16x8 b = cvt8(wop + ks * 32);
      acc = __builtin_amdgcn_mfma_f32_16x16x32_bf16(a, b, acc, 0, 0, 0);
    }
#pragma unroll
    for (int r = 0; r < 4; ++r) hred[k4 * 4 + r][wv * 16 + l15] = acc[r];
    __syncthreads();
    {
      f32x4 v = *reinterpret_cast<const f32x4*>(&hred[erow][ec]);
      v += *reinterpret_cast<const f32x4*>(Wo_b + C0 + ec);
      *reinterpret_cast<f32x4*>(out + (size_t)(R0 + erow) * O_ + C0 + ec) = v;
    }
  }
}

// ---------------------------------------------------------------------------
extern "C" void kernel_launch(void* const* d_in, const int* in_sizes, int n_in,
                              void* d_out, int out_size, void* d_ws, size_t ws_size,
                              hipStream_t stream) {
  const float* seq  = (const float*)d_in[0];
  const float* Wh_w = (const float*)d_in[1];
  const float* Wh_b = (const float*)d_in[2];
  const float* Wi_w = (const float*)d_in[3];
  const float* Wi_b = (const float*)d_in[4];
  const float* Wo_w = (const float*)d_in[5];
  const float* Wo_b = (const float*)d_in[6];

  char* ws = (char*)d_ws;
  unsigned short* hbuf   = (unsigned short*)ws; ws += (size_t)2 * HB * 2;  // 2 MB
  unsigned*       flags  = (unsigned*)ws;       ws += 4096;                // 32 x 32 words
  unsigned short* seq_bf = (unsigned short*)ws;                            // 32 MB

  prep_kernel<<<2048, 256, 0, stream>>>(seq, seq_bf, flags);
  rnn_fused<<<256, 512, 0, stream>>>(seq_bf, Wh_w, Wh_b, Wi_w, Wi_b, Wo_w, Wo_b,
                                     hbuf, flags, (float*)d_out);
}